// Round 1
// baseline (402.547 us; speedup 1.0000x reference)
//
#include <hip/hip_runtime.h>
#include <math.h>

#define EPSF 1e-7f
#define AA 3
#define CC 80
#define FOUR_OVER_PI2 0.4052847345693511f

__device__ __forceinline__ float sigmoidf_(float x) { return 1.0f / (1.0f + expf(-x)); }

__device__ __forceinline__ float bcef_(float x, float t) {
    // numerically-stable BCEWithLogits, single element
    return fmaxf(x, 0.0f) - x * t + log1pf(expf(-fabsf(x)));
}

__device__ __forceinline__ void block_reduce_add2(double v0, double v1, double* d0, double* d1) {
    __shared__ double s0[8], s1[8];
    const int lane = threadIdx.x & 63;
    const int wid  = threadIdx.x >> 6;
    #pragma unroll
    for (int off = 32; off > 0; off >>= 1) {
        v0 += __shfl_down(v0, off);
        v1 += __shfl_down(v1, off);
    }
    if (lane == 0) { s0[wid] = v0; s1[wid] = v1; }
    __syncthreads();
    if (threadIdx.x == 0) {
        const int nw = blockDim.x >> 6;
        double a = 0.0, b = 0.0;
        for (int w = 0; w < nw; ++w) { a += s0[w]; b += s1[w]; }
        atomicAdd(d0, a);
        atomicAdd(d1, b);
    }
}

__device__ __forceinline__ void block_reduce_add1(double v0, double* d0) {
    __shared__ double s0[8];
    const int lane = threadIdx.x & 63;
    const int wid  = threadIdx.x >> 6;
    #pragma unroll
    for (int off = 32; off > 0; off >>= 1) v0 += __shfl_down(v0, off);
    if (lane == 0) s0[wid] = v0;
    __syncthreads();
    if (threadIdx.x == 0) {
        const int nw = blockDim.x >> 6;
        double a = 0.0;
        for (int w = 0; w < nw; ++w) a += s0[w];
        atomicAdd(d0, a);
    }
}

// Per-target: gather box+cls logits, CIoU, cls-BCE, scatter tobj (last-target-wins).
__global__ __launch_bounds__(256) void target_kernel(
    const float* __restrict__ box, const float* __restrict__ cls,
    const int* __restrict__ tb, const int* __restrict__ ta,
    const int* __restrict__ tgy, const int* __restrict__ tgx,
    const int* __restrict__ ttc,
    const float* __restrict__ tbox, const float* __restrict__ anc,
    unsigned long long* __restrict__ tobj,
    double* __restrict__ accBox, double* __restrict__ accCls,
    int N, int H, int W)
{
    const int j = blockIdx.x * blockDim.x + threadIdx.x;
    float lb = 0.0f, lc = 0.0f;
    if (j < N) {
        const int b = tb[j], a = ta[j], gy = tgy[j], gx = tgx[j], tc = ttc[j];
        const long long cell = ((long long)((b * AA + a) * H + gy)) * W + gx;

        const float* bp = box + cell * 4;
        const float bx = bp[0], by = bp[1], bw = bp[2], bh = bp[3];

        const float px = sigmoidf_(bx) * 2.0f - 0.5f;
        const float py = sigmoidf_(by) * 2.0f - 0.5f;
        const float sw = sigmoidf_(bw) * 2.0f;
        const float sh = sigmoidf_(bh) * 2.0f;
        const float pw = sw * sw * anc[j * 2 + 0];
        const float ph = sh * sh * anc[j * 2 + 1];

        const float tx = tbox[j * 4 + 0], ty = tbox[j * 4 + 1];
        const float tw = tbox[j * 4 + 2], th = tbox[j * 4 + 3];

        // CIoU (mirror reference's formulation)
        const float x1a = px - pw * 0.5f, y1a = py - ph * 0.5f;
        const float x2a = px + pw * 0.5f, y2a = py + ph * 0.5f;
        const float x1b = tx - tw * 0.5f, y1b = ty - th * 0.5f;
        const float x2b = tx + tw * 0.5f, y2b = ty + th * 0.5f;

        const float iw = fmaxf(fminf(x2a, x2b) - fmaxf(x1a, x1b), 0.0f);
        const float ih = fmaxf(fminf(y2a, y2b) - fmaxf(y1a, y1b), 0.0f);
        const float inter = iw * ih;
        const float uni = (x2a - x1a) * (y2a - y1a) + (x2b - x1b) * (y2b - y1b) - inter;
        const float iou = inter / (uni + EPSF);
        const float cw = fmaxf(x2a, x2b) - fminf(x1a, x1b);
        const float ch = fmaxf(y2a, y2b) - fminf(y1a, y1b);
        const float diag = cw * cw + ch * ch + EPSF;
        const float dcx = (x1a + x2a) * 0.5f - (x1b + x2b) * 0.5f;
        const float dcy = (y1a + y2a) * 0.5f - (y1b + y2b) * 0.5f;
        const float cent = dcx * dcx + dcy * dcy;
        const float at = atanf((x2a - x1a) / ((y2a - y1a) + EPSF))
                       - atanf((x2b - x1b) / ((y2b - y1b) + EPSF));
        const float v = FOUR_OVER_PI2 * at * at;
        const float alpha = v / (v - iou + 1.0f + EPSF);
        const float ciou = iou - (cent / diag + v * alpha);

        lb = 1.0f - ciou;

        // scatter tobj with deterministic last-target-wins:
        // pack (j+1) in the high 32 bits, float bits of clip(ciou,0) in the low.
        const float ioc = fmaxf(ciou, 0.0f);
        const unsigned long long pk =
            ((unsigned long long)(unsigned)(j + 1) << 32) |
            (unsigned long long)__float_as_uint(ioc);
        atomicMax(tobj + cell, pk);

        // 80-class BCE (one-hot target at tc)
        const float* cp = cls + cell * CC;
        float s = 0.0f;
        #pragma unroll 8
        for (int c = 0; c < CC; ++c) {
            const float x = cp[c];
            const float t = (c == tc) ? 1.0f : 0.0f;
            s += bcef_(x, t);
        }
        lc = s;
    }
    block_reduce_add2((double)lb, (double)lc, accBox, accCls);
}

// Full-grid objectness BCE: cnf vs tobj (tobj low 32 bits are float bits; 0 => 0.0f).
__global__ __launch_bounds__(256) void obj_kernel(
    const float* __restrict__ cnf,
    const unsigned long long* __restrict__ tobj,
    double* __restrict__ accObj, int n4)
{
    const int stride = gridDim.x * blockDim.x;
    double s = 0.0;
    for (int idx = blockIdx.x * blockDim.x + threadIdx.x; idx < n4; idx += stride) {
        const float4 x4 = ((const float4*)cnf)[idx];
        const unsigned long long* tp = tobj + (long long)idx * 4;
        float xs[4] = {x4.x, x4.y, x4.z, x4.w};
        float ps = 0.0f;
        #pragma unroll
        for (int k = 0; k < 4; ++k) {
            const unsigned long long pk = tp[k];
            const float t = __uint_as_float((unsigned)(pk & 0xFFFFFFFFull));
            ps += bcef_(xs[k], t);
        }
        s += (double)ps;
    }
    block_reduce_add1(s, accObj);
}

__global__ void finalize_kernel(const double* __restrict__ acc, float* __restrict__ out) {
    if (threadIdx.x == 0 && blockIdx.x == 0) {
        const double lbox = acc[0] / 6000.0 + acc[1] / 4000.0 + acc[2] / 2000.0;
        const double lobj = (acc[3] / 614400.0) * 4.0
                          + (acc[4] / 153600.0) * 1.0
                          + (acc[5] /  38400.0) * 0.4;
        const double lcls = acc[6] / 480000.0 + acc[7] / 320000.0 + acc[8] / 160000.0;
        out[0] = (float)(lbox * 0.05 * 32.0);
        out[1] = (float)(lobj * 0.7 * 32.0);
        out[2] = (float)(lcls * 0.3 * 32.0);
    }
}

extern "C" void kernel_launch(void* const* d_in, const int* in_sizes, int n_in,
                              void* d_out, int out_size, void* d_ws, size_t ws_size,
                              hipStream_t stream) {
    // setup_inputs() dict order per scale i: box, cnf, cls, b, a, gy, gx, tcls, tbox, anc
    const int NS[3]    = {6000, 4000, 2000};
    const int HS[3]    = {80, 40, 20};
    const int CELLS[3] = {32 * AA * 80 * 80, 32 * AA * 40 * 40, 32 * AA * 20 * 20};

    double* acc = (double*)d_ws;  // [0..2]=box, [3..5]=obj, [6..8]=cls
    unsigned long long* tobj0 = (unsigned long long*)((char*)d_ws + 128);
    unsigned long long* tobj1 = tobj0 + CELLS[0];
    unsigned long long* tobj2 = tobj1 + CELLS[1];
    unsigned long long* tobjs[3] = {tobj0, tobj1, tobj2};

    const size_t zero_bytes = 128 + (size_t)(CELLS[0] + CELLS[1] + CELLS[2]) * 8;
    hipMemsetAsync(d_ws, 0, zero_bytes, stream);

    for (int i = 0; i < 3; ++i) {
        const int base = i * 10;
        const float* box  = (const float*)d_in[base + 0];
        const int*   b    = (const int*)  d_in[base + 3];
        const int*   a    = (const int*)  d_in[base + 4];
        const int*   gy   = (const int*)  d_in[base + 5];
        const int*   gx   = (const int*)  d_in[base + 6];
        const int*   tcls = (const int*)  d_in[base + 7];
        const float* tbox = (const float*)d_in[base + 8];
        const float* anc  = (const float*)d_in[base + 9];
        const float* cls  = (const float*)d_in[base + 2];

        const int N = NS[i];
        const int grid = (N + 255) / 256;
        target_kernel<<<grid, 256, 0, stream>>>(box, cls, b, a, gy, gx, tcls, tbox, anc,
                                                tobjs[i], acc + i, acc + 6 + i,
                                                N, HS[i], HS[i]);
    }

    for (int i = 0; i < 3; ++i) {
        const int base = i * 10;
        const float* cnf = (const float*)d_in[base + 1];
        const int n4 = CELLS[i] / 4;
        const int grid = min((n4 + 255) / 256, 256);
        obj_kernel<<<grid, 256, 0, stream>>>(cnf, tobjs[i], acc + 3 + i, n4);
    }

    finalize_kernel<<<1, 64, 0, stream>>>(acc, (float*)d_out);
}

// Round 2
// 399.185 us; speedup vs baseline: 1.0084x; 1.0084x over previous
//
#include <hip/hip_runtime.h>
#include <math.h>

#define EPSF 1e-7f
#define FOUR_OVER_PI2 0.4052847345693511f

struct Params {
    const float* box[3];
    const float* cnf[3];
    const float* cls[3];
    const float* tbox[3];
    const float* anc[3];
    const int* tb[3];
    const int* ta[3];
    const int* tgy[3];
    const int* tgx[3];
    const int* ttc[3];
    unsigned* tobj;     // [806400] winner id per cell (0 = none, else global j+1)
    float* iouv;        // [12000] clip(ciou,0) per target
    unsigned* cellv;    // [12000] global cell index per target
    double* acc;        // [3]: box, cls, obj (weighted sums)
    unsigned* counter;  // finalize gate
    float* out;         // [3]
};

__device__ __forceinline__ float softplus_(float x) {
    return fmaxf(x, 0.0f) + log1pf(expf(-fabsf(x)));   // == bce(x, 0)
}
__device__ __forceinline__ float sigmoidf_(float x) { return 1.0f / (1.0f + expf(-x)); }

__device__ __forceinline__ void block_reduce_add2(double v0, double v1, double* d0, double* d1) {
    __shared__ double s0[8], s1[8];
    const int lane = threadIdx.x & 63;
    const int wid  = threadIdx.x >> 6;
    #pragma unroll
    for (int off = 32; off > 0; off >>= 1) {
        v0 += __shfl_down(v0, off);
        v1 += __shfl_down(v1, off);
    }
    if (lane == 0) { s0[wid] = v0; s1[wid] = v1; }
    __syncthreads();
    if (threadIdx.x == 0) {
        const int nw = blockDim.x >> 6;
        double a = 0.0, b = 0.0;
        for (int w = 0; w < nw; ++w) { a += s0[w]; b += s1[w]; }
        atomicAdd(d0, a);
        atomicAdd(d1, b);
    }
}

__device__ __forceinline__ void block_reduce_add1(double v0, double* d0) {
    __shared__ double s0[8];
    const int lane = threadIdx.x & 63;
    const int wid  = threadIdx.x >> 6;
    #pragma unroll
    for (int off = 32; off > 0; off >>= 1) v0 += __shfl_down(v0, off);
    if (lane == 0) s0[wid] = v0;
    __syncthreads();
    if (threadIdx.x == 0) {
        const int nw = blockDim.x >> 6;
        double a = 0.0;
        for (int w = 0; w < nw; ++w) a += s0[w];
        atomicAdd(d0, a);
    }
}

// One thread per target (all 3 scales fused).
__global__ __launch_bounds__(256) void targets_kernel(Params P)
{
    const int j = blockIdx.x * blockDim.x + threadIdx.x;
    double lb = 0.0, lc = 0.0;
    if (j < 12000) {
        int i, jj;
        if (j < 6000)       { i = 0; jj = j; }
        else if (j < 10000) { i = 1; jj = j - 6000; }
        else                { i = 2; jj = j - 10000; }
        const int H    = (i == 0) ? 80 : (i == 1) ? 40 : 20;
        const int gofs = (i == 0) ? 0  : (i == 1) ? 614400 : 768000;
        const double wbox = (i == 0) ? (1.0 / 6000.0) : (i == 1) ? (1.0 / 4000.0) : (1.0 / 2000.0);
        const double wcls = wbox * (1.0 / 80.0);

        const int b  = P.tb[i][jj],  a  = P.ta[i][jj];
        const int gy = P.tgy[i][jj], gx = P.tgx[i][jj], tc = P.ttc[i][jj];
        const int cell = ((b * 3 + a) * H + gy) * H + gx;   // W == H

        const float4 b4 = ((const float4*)P.box[i])[cell];
        const float2 an = ((const float2*)P.anc[i])[jj];
        const float4 t4 = ((const float4*)P.tbox[i])[jj];

        const float px = sigmoidf_(b4.x) * 2.0f - 0.5f;
        const float py = sigmoidf_(b4.y) * 2.0f - 0.5f;
        const float sw = sigmoidf_(b4.z) * 2.0f;
        const float sh = sigmoidf_(b4.w) * 2.0f;
        const float pw = sw * sw * an.x;
        const float ph = sh * sh * an.y;

        const float x1a = px - pw * 0.5f, y1a = py - ph * 0.5f;
        const float x2a = px + pw * 0.5f, y2a = py + ph * 0.5f;
        const float x1b = t4.x - t4.z * 0.5f, y1b = t4.y - t4.w * 0.5f;
        const float x2b = t4.x + t4.z * 0.5f, y2b = t4.y + t4.w * 0.5f;

        const float iw = fmaxf(fminf(x2a, x2b) - fmaxf(x1a, x1b), 0.0f);
        const float ih = fmaxf(fminf(y2a, y2b) - fmaxf(y1a, y1b), 0.0f);
        const float inter = iw * ih;
        const float uni = (x2a - x1a) * (y2a - y1a) + (x2b - x1b) * (y2b - y1b) - inter;
        const float iou = inter / (uni + EPSF);
        const float cw = fmaxf(x2a, x2b) - fminf(x1a, x1b);
        const float ch = fmaxf(y2a, y2b) - fminf(y1a, y1b);
        const float diag = cw * cw + ch * ch + EPSF;
        const float dcx = (x1a + x2a) * 0.5f - (x1b + x2b) * 0.5f;
        const float dcy = (y1a + y2a) * 0.5f - (y1b + y2b) * 0.5f;
        const float cent = dcx * dcx + dcy * dcy;
        const float at = atanf((x2a - x1a) / ((y2a - y1a) + EPSF))
                       - atanf((x2b - x1b) / ((y2b - y1b) + EPSF));
        const float v = FOUR_OVER_PI2 * at * at;
        const float alpha = v / (v - iou + 1.0f + EPSF);
        const float ciou = iou - (cent / diag + v * alpha);

        lb = (double)(1.0f - ciou) * wbox;

        P.iouv[j]  = fmaxf(ciou, 0.0f);
        P.cellv[j] = (unsigned)(gofs + cell);
        atomicMax(P.tobj + gofs + cell, (unsigned)(j + 1));   // last target (max j) wins

        // sum_c bce(x_c, onehot_tc) == sum_c softplus(x_c) - x_tc
        const float* cbase = P.cls[i] + (long long)cell * 80;
        const float4* cp = (const float4*)cbase;
        float s = 0.0f;
        #pragma unroll
        for (int q = 0; q < 20; ++q) {
            const float4 x4 = cp[q];
            s += softplus_(x4.x) + softplus_(x4.y) + softplus_(x4.z) + softplus_(x4.w);
        }
        s -= cbase[tc];
        lc = (double)s * wcls;
    }
    block_reduce_add2(lb, lc, P.acc + 0, P.acc + 1);
}

// Full-grid objectness softplus sum + per-target -x*t correction + last-block finalize.
__global__ __launch_bounds__(256) void obj_kernel(Params P)
{
    const int t = blockIdx.x * blockDim.x + threadIdx.x;
    double s = 0.0;
    if (t < 201600) {
        int i, lidx;
        if (t < 153600)      { i = 0; lidx = t; }
        else if (t < 192000) { i = 1; lidx = t - 153600; }
        else                 { i = 2; lidx = t - 192000; }
        const double w = (i == 0) ? (4.0 / 614400.0)
                       : (i == 1) ? (1.0 / 153600.0)
                                  : (0.4 / 38400.0);
        const float4 x4 = ((const float4*)P.cnf[i])[lidx];
        const float ps = softplus_(x4.x) + softplus_(x4.y) + softplus_(x4.z) + softplus_(x4.w);
        s = (double)ps * w;
    }
    if (t < 12000) {
        const int i = (t < 6000) ? 0 : (t < 10000) ? 1 : 2;
        const unsigned gcell = P.cellv[t];
        if (P.tobj[gcell] == (unsigned)(t + 1)) {
            const unsigned gofs = (i == 0) ? 0u : (i == 1) ? 614400u : 768000u;
            const double w = (i == 0) ? (4.0 / 614400.0)
                           : (i == 1) ? (1.0 / 153600.0)
                                      : (0.4 / 38400.0);
            const float x = P.cnf[i][gcell - gofs];
            s -= (double)(x * P.iouv[t]) * w;   // bce(x,t) - bce(x,0) = -x*t
        }
    }
    block_reduce_add1(s, P.acc + 2);

    __shared__ int amLast;
    __threadfence();
    if (threadIdx.x == 0)
        amLast = (atomicAdd(P.counter, 1u) == gridDim.x - 1);
    __syncthreads();
    if (amLast && threadIdx.x == 0) {
        __threadfence();
        const double lbox = P.acc[0], lcls = P.acc[1], lobj = P.acc[2];
        P.out[0] = (float)(lbox * (0.05 * 32.0));
        P.out[1] = (float)(lobj * (0.7 * 32.0));
        P.out[2] = (float)(lcls * (0.3 * 32.0));
    }
}

extern "C" void kernel_launch(void* const* d_in, const int* in_sizes, int n_in,
                              void* d_out, int out_size, void* d_ws, size_t ws_size,
                              hipStream_t stream) {
    // setup_inputs() order per scale i: box, cnf, cls, b, a, gy, gx, tcls, tbox, anc
    Params P;
    for (int i = 0; i < 3; ++i) {
        const int base = i * 10;
        P.box[i]  = (const float*)d_in[base + 0];
        P.cnf[i]  = (const float*)d_in[base + 1];
        P.cls[i]  = (const float*)d_in[base + 2];
        P.tb[i]   = (const int*)  d_in[base + 3];
        P.ta[i]   = (const int*)  d_in[base + 4];
        P.tgy[i]  = (const int*)  d_in[base + 5];
        P.tgx[i]  = (const int*)  d_in[base + 6];
        P.ttc[i]  = (const int*)  d_in[base + 7];
        P.tbox[i] = (const float*)d_in[base + 8];
        P.anc[i]  = (const float*)d_in[base + 9];
    }
    char* ws = (char*)d_ws;
    P.acc     = (double*)ws;                       // 24 B
    P.counter = (unsigned*)(ws + 24);              // 4 B
    P.tobj    = (unsigned*)(ws + 128);             // 806400 * 4 B
    P.iouv    = (float*)   (ws + 128 + 806400 * 4);
    P.cellv   = (unsigned*)(ws + 128 + 806400 * 4 + 12000 * 4);
    P.out     = (float*)d_out;

    hipMemsetAsync(d_ws, 0, 128 + 806400 * 4, stream);  // acc + counter + tobj

    targets_kernel<<<(12000 + 255) / 256, 256, 0, stream>>>(P);
    obj_kernel<<<(201600 + 255) / 256, 256, 0, stream>>>(P);
}